// Round 2
// baseline (217.511 us; speedup 1.0000x reference)
//
#include <hip/hip_runtime.h>
#include <stdint.h>

// FusedMultiPool: out[b,s,h,w] = max_{k<K} x[b, idx[s,k], h, w]
// B=32, C=256, H=64, W=64, S=128, K=8. fp32.
//
// v3: persistent double-buffered streaming (guide T3 minimum-2-phase).
// v1 (direct gather) and v2 (LDS inversion, __syncthreads 2-phase) both
// landed at ~the same time: HBM traffic is compulsory in both (~134 MB rd
// + 67 MB wr); v2's limiter is the barrier's full vmcnt drain serializing
// load->compute->store per tile. Here: 512 persistent blocks (2/CU),
// each owns 8 consecutive tiles; tile j+1 is async-staged via
// global_load_lds into the alternate LDS buffer WHILE tile j computes;
// the vmcnt(0) drain sits AFTER compute (raw s_barrier, not
// __syncthreads), so the HBM read stream never stops.
//
// LDS: 2 x 32 KiB tile buffers + 4 KiB idx = 68 KiB -> exactly 2 blocks/CU
// (136 KiB of 160), 8 waves/CU. Grid 512 = all blocks resident, persistent.

constexpr int Bb = 32, Cc = 256, Hh = 64, Ww = 64, Ss = 128, Kk = 8;
constexpr int HW4 = (Hh * Ww) / 4;   // 1024 float4 per channel plane
constexpr int T4  = 8;               // float4 positions per tile (128 B)
constexpr int NT  = HW4 / T4;        // 128 tiles per b
constexpr int TPB = 8;               // tiles per persistent block
constexpr int NBLK = Bb * NT / TPB;  // 512 blocks

__device__ __forceinline__ void async_copy16(float4* lds_dst, const float4* g_src) {
    // direct global->LDS, 16 B per lane; LDS dest is wave-uniform base + lane*16
    __builtin_amdgcn_global_load_lds(
        (const __attribute__((address_space(1))) void*)g_src,
        (__attribute__((address_space(3))) void*)lds_dst,
        16, 0, 0);
}

__global__ __launch_bounds__(256, 2) void fmp_kernel(
    const float4* __restrict__ x4,
    const int*    __restrict__ idx,
    float4*       __restrict__ out4)
{
    __shared__ float4 lx[2][Cc * T4];      // 2 x 32 KiB: lx[buf][c*8 + t]
    __shared__ int4   lidx4[Ss * Kk / 4];  // 4 KiB

    const int tid   = threadIdx.x;
    const int b     = blockIdx.x >> 4;              // 16 blocks per b
    const int tile0 = (blockIdx.x & 15) * TPB;      // first tile of this block

    // stage channel-index sets once (1024 ints, coalesced)
    lidx4[tid] = ((const int4*)idx)[tid];

    // per-thread staging source pointers; advance T4 float4 (128 B) per tile.
    // flat = i*256 + tid -> each wave's 64 lanes are contiguous in LDS order
    // (global_load_lds requirement: linear lane-order destination).
    const float4* __restrict__ xb = x4 + (size_t)b * (Cc * HW4) + tile0 * T4;
    const float4* gsrc[8];
    #pragma unroll
    for (int i = 0; i < 8; ++i) {
        const int flat = i * 256 + tid;
        gsrc[i] = xb + (size_t)(flat >> 3) * HW4 + (flat & (T4 - 1));
    }
    const int wbase = (tid >> 6) * 64;   // wave-uniform LDS float4 offset

    // prologue: stage tile0 into buf 0
    #pragma unroll
    for (int i = 0; i < 8; ++i)
        async_copy16(&lx[0][i * 256 + wbase], gsrc[i]);

    asm volatile("s_waitcnt vmcnt(0) lgkmcnt(0)" ::: "memory");
    __builtin_amdgcn_s_barrier();

    const int t  = tid & (T4 - 1);       // float4 position within tile
    const int sg = tid >> 3;             // 0..31: s-group
    float4* __restrict__ op = out4 + (size_t)b * (Ss * HW4) + tile0 * T4 + t;

#define FMAX4(m, c) { const float4 v = L[(c) * T4 + t];           \
        m.x = fmaxf(m.x, v.x); m.y = fmaxf(m.y, v.y);             \
        m.z = fmaxf(m.z, v.z); m.w = fmaxf(m.w, v.w); }

    #pragma unroll
    for (int j = 0; j < TPB; ++j) {
        const int cur = j & 1;

        // issue next tile's loads FIRST -> in flight across this tile's compute
        if (j + 1 < TPB) {
            #pragma unroll
            for (int i = 0; i < 8; ++i)
                async_copy16(&lx[cur ^ 1][i * 256 + wbase],
                             gsrc[i] + (size_t)(j + 1) * T4);
        }

        // compute tile j from lx[cur]
        const float4* __restrict__ L = lx[cur];
        #pragma unroll
        for (int pass = 0; pass < 4; ++pass) {
            const int  s  = pass * 32 + sg;
            const int4 i0 = lidx4[s * 2];
            const int4 i1 = lidx4[s * 2 + 1];
            float4 m = L[i0.x * T4 + t];
            FMAX4(m, i0.y); FMAX4(m, i0.z); FMAX4(m, i0.w);
            FMAX4(m, i1.x); FMAX4(m, i1.y); FMAX4(m, i1.z); FMAX4(m, i1.w);
            op[(size_t)s * HW4 + j * T4] = m;
        }

        // drain AFTER compute: next-tile loads (and our stores) complete,
        // then all waves cross -> buf swap is safe.
        asm volatile("s_waitcnt vmcnt(0)" ::: "memory");
        __builtin_amdgcn_s_barrier();
    }
#undef FMAX4
}

extern "C" void kernel_launch(void* const* d_in, const int* in_sizes, int n_in,
                              void* d_out, int out_size, void* d_ws, size_t ws_size,
                              hipStream_t stream) {
    const float4* x4  = (const float4*)d_in[0];
    const int*    idx = (const int*)d_in[1];
    float4*       o4  = (float4*)d_out;

    fmp_kernel<<<NBLK, 256, 0, stream>>>(x4, idx, o4);
}